// Round 4
// baseline (302.480 us; speedup 1.0000x reference)
//
#include <hip/hip_runtime.h>
#include <stdint.h>

#define BT      128
#define NPATCH  256
#define DV      1024
#define NB      4
#define DB      256
#define NH16    16
#define SCALE   0.125f
#define LNEPS   1e-5f

// ---- ws layout (float element offsets), total ~38.7 MB ----
#define OFF_GWQ    0u          // 16*1024
#define OFF_BWS    16384u      // 16384 bf16 = 8192 floats
#define OFF_S      24576u      // 16
#define OFF_CB     24592u      // 16
#define OFF_PSC    24608u      // 512
#define OFF_DRAW   25120u      // 32768*16
#define OFF_STATS  549408u     // 32768*2 (mu,rstd)
#define OFF_W      614944u     // 128*16*256 (attn*rstd)
#define OFF_CV     1139232u    // 128*16
#define OFF_DIV    1141280u    // 768
#define OFF_XBAR   1142048u    // 4 slices * 2097152
#define OFF_POOL   9530656u    // 4*128*256
#define XSLICE     2097152u

#define LROW 264               // bf16 per LDS row (256 + 8 pad)

typedef short bf16x8 __attribute__((ext_vector_type(8)));
typedef float f32x4  __attribute__((ext_vector_type(4)));

__device__ __forceinline__ short f2bf(float f) {   // RNE
    union { float f; unsigned u; } v; v.f = f;
    unsigned u = v.u;
    unsigned r = (u + 0x7fffu + ((u >> 16) & 1u)) >> 16;
    return (short)r;
}

// pack two floats -> two truncated bf16 in one v_perm_b32
__device__ __forceinline__ unsigned pk2(float lo, float hi) {
    union { float f; unsigned u; } a, b; a.f = lo; b.f = hi;
    return __builtin_amdgcn_perm(b.u, a.u, 0x07060302u);
}

// ---- P: partial wq dots, 256 blocks = 16 nh x 16 i-chunks of 64 rows ----
__global__ __launch_bounds__(256) void kP(const float* __restrict__ Wk,
                                          const float* __restrict__ q,
                                          const float* __restrict__ g,
                                          const float* __restrict__ b,
                                          float* __restrict__ ws) {
    const int nh = blockIdx.x >> 4, ich = blockIdx.x & 15;
    const int n = nh >> 2, h = nh & 3;
    __shared__ float qs[64];
    __shared__ float redS[4], redC[4];
    const int t = threadIdx.x;
    if (t < 64) qs[t] = q[nh * 64 + t];
    __syncthreads();
    const int r = t >> 2, qd = t & 3;
    const int i = ich * 64 + r;
    const float* wrow = Wk + ((size_t)n * DV + i) * DB + h * 64 + qd * 16;
    float acc = 0.f;
    #pragma unroll
    for (int d = 0; d < 16; d += 4) {
        float4 w4 = *(const float4*)(wrow + d);
        acc += w4.x * qs[qd * 16 + d]     + w4.y * qs[qd * 16 + d + 1]
             + w4.z * qs[qd * 16 + d + 2] + w4.w * qs[qd * 16 + d + 3];
    }
    acc += __shfl_xor(acc, 1);
    acc += __shfl_xor(acc, 2);
    float gw = g[i] * acc;
    if (qd == 0) ws[OFF_GWQ + nh * DV + i] = gw;
    float mS = (qd == 0) ? gw : 0.f;
    float mC = (qd == 0) ? b[i] * acc : 0.f;
    #pragma unroll
    for (int dd = 4; dd < 64; dd <<= 1) { mS += __shfl_xor(mS, dd); mC += __shfl_xor(mC, dd); }
    const int wave = t >> 6, lane = t & 63;
    if (lane == 0) { redS[wave] = mS; redC[wave] = mC; }
    __syncthreads();
    if (t == 0) {
        ws[OFF_PSC + (nh * 16 + ich) * 2 + 0] = redS[0] + redS[1] + redS[2] + redS[3];
        ws[OFF_PSC + (nh * 16 + ich) * 2 + 1] = redC[0] + redC[1] + redC[2] + redC[3];
    }
}

// ---- P2: blocks 0..15 pack B-frags; block 16 reduces S/Cb ----
__global__ __launch_bounds__(1024) void kP2(const float* __restrict__ q,
                                            const float* __restrict__ bk,
                                            float* __restrict__ ws) {
    const int blk = blockIdx.x;
    const int t = threadIdx.x;
    if (blk == 16) {
        if (t < 16) {
            const int nh = t, n = nh >> 2, h = nh & 3;
            float S = 0.f, C = 0.f;
            for (int ich = 0; ich < 16; ++ich) {
                S += ws[OFF_PSC + (nh * 16 + ich) * 2 + 0];
                C += ws[OFF_PSC + (nh * 16 + ich) * 2 + 1];
            }
            float bkq = 0.f;
            for (int d = 0; d < 64; ++d) bkq += bk[n * DB + h * 64 + d] * q[nh * 64 + d];
            ws[OFF_S + nh]  = S;
            ws[OFF_CB + nh] = C + bkq;
        }
        return;
    }
    unsigned short* bws = (unsigned short*)(ws + OFF_BWS);
    const float* gwq = ws + OFF_GWQ;
    const int idx = blk * 1024 + t;
    const int j = idx & 7, lane = (idx >> 3) & 63, kt = idx >> 9;
    const int nh = lane & 15;
    const int k = kt * 32 + ((lane >> 4) * 8) + j;
    bws[idx] = (unsigned short)f2bf(gwq[nh * DV + k]);
}

// ---- A: LDS-staged coalesced MFMA scores + LN stats, full K per block ----
// 512 blocks x 256 threads; block = 64 rows; wave w owns rows w*16..w*16+15
__global__ __launch_bounds__(256) void kA(const float* __restrict__ x,
                                          float* __restrict__ ws) {
    __shared__ unsigned short xs[2][64 * LROW];   // 67.6 KB double-buffered bf16
    const int t = threadIdx.x;
    const int wv = t >> 6, lane = t & 63;
    const int m = lane & 15, oct = lane >> 4;
    const int row0 = blockIdx.x * 64;
    const bf16x8* bfp = (const bf16x8*)((const unsigned short*)(ws + OFF_BWS));
    const float* xb = x + (size_t)row0 * DV;

    float sum[16], sq[16];
    #pragma unroll
    for (int i = 0; i < 16; ++i) { sum[i] = 0.f; sq[i] = 0.f; }
    f32x4 acc = {0.f, 0.f, 0.f, 0.f};

    auto stage = [&](int c, int buf) {
        #pragma unroll
        for (int i = 0; i < 16; ++i) {
            const int row = i * 4 + wv;
            float4 v = *(const float4*)(xb + (size_t)row * DV + c * 256 + lane * 4);
            sum[i] += v.x + v.y + v.z + v.w;
            sq[i]  += v.x * v.x + v.y * v.y + v.z * v.z + v.w * v.w;
            uint2 pk; pk.x = pk2(v.x, v.y); pk.y = pk2(v.z, v.w);
            *(uint2*)&xs[buf][row * LROW + lane * 4] = pk;
        }
    };
    auto comp = [&](int c, int buf) {
        #pragma unroll
        for (int kt = 0; kt < 8; ++kt) {
            bf16x8 af = *(const bf16x8*)&xs[buf][(wv * 16 + m) * LROW + kt * 32 + oct * 8];
            bf16x8 bf = bfp[(c * 8 + kt) * 64 + lane];
            acc = __builtin_amdgcn_mfma_f32_16x16x32_bf16(af, bf, acc, 0, 0, 0);
        }
    };

    stage(0, 0);
    __syncthreads();
    #pragma unroll
    for (int c = 0; c < 4; ++c) {
        if (c < 3) stage(c + 1, (c + 1) & 1);
        comp(c, c & 1);
        __syncthreads();
    }

    // raw dots: C-layout col=lane&15 (nh), row=(lane>>4)*4+r within wave tile
    #pragma unroll
    for (int r = 0; r < 4; ++r)
        ws[OFF_DRAW + (size_t)(row0 + wv * 16 + oct * 4 + r) * 16 + m] = acc[r];

    // LN stats: row i*4+wv partials live across this wave's 64 lanes
    #pragma unroll
    for (int i = 0; i < 16; ++i) {
        float s = sum[i], q2 = sq[i];
        #pragma unroll
        for (int d = 1; d < 64; d <<= 1) { s += __shfl_xor(s, d); q2 += __shfl_xor(q2, d); }
        if (lane == 0) {
            const int row = row0 + i * 4 + wv;
            const float mu  = s * (1.f / 1024.f);
            const float var = q2 * (1.f / 1024.f) - mu * mu;
            float2 st; st.x = mu; st.y = rsqrtf(var + LNEPS);
            *(float2*)(ws + OFF_STATS + (size_t)row * 2) = st;
        }
    }
}

// ---- B: scores -> softmax -> W=attn*rstd, CV, diversity ----
__global__ __launch_bounds__(256) void kB(float* __restrict__ ws) {
    const int bt = blockIdx.x;
    const int t = threadIdx.x;            // patch p
    __shared__ __attribute__((aligned(16))) float s_s[NH16 * NPATCH];
    __shared__ __attribute__((aligned(16))) float aavg[NB * NPATCH];
    __shared__ __attribute__((aligned(16))) float rstd_s[NPATCH];
    __shared__ __attribute__((aligned(16))) float mrs[NPATCH];
    __shared__ float Ss[NH16], Cbs[NH16];
    if (t < NH16) Ss[t] = ws[OFF_S + t];
    else if (t < 32) Cbs[t - 16] = ws[OFF_CB + (t - 16)];
    const size_t row = (size_t)bt * NPATCH + t;
    const float2 st = *(const float2*)(ws + OFF_STATS + row * 2);
    const float mu = st.x, rstd = st.y;
    rstd_s[t] = rstd;
    mrs[t] = mu * rstd;
    __syncthreads();
    const float* dr = ws + OFF_DRAW + row * 16;
    #pragma unroll
    for (int nh = 0; nh < NH16; ++nh) {
        float D = dr[nh];
        s_s[nh * NPATCH + t] = (rstd * (D - mu * Ss[nh]) + Cbs[nh]) * SCALE;
    }
    __syncthreads();
    const int wave = t >> 6, lane = t & 63;
    for (int r = 0; r < 4; ++r) {
        const int nh = wave * 4 + r;
        float4 v = *(float4*)&s_s[nh * NPATCH + lane * 4];
        float mx = fmaxf(fmaxf(v.x, v.y), fmaxf(v.z, v.w));
        for (int d = 1; d < 64; d <<= 1) mx = fmaxf(mx, __shfl_xor(mx, d));
        float e0 = __expf(v.x - mx), e1 = __expf(v.y - mx);
        float e2 = __expf(v.z - mx), e3 = __expf(v.w - mx);
        float s = e0 + e1 + e2 + e3;
        for (int d = 1; d < 64; d <<= 1) s += __shfl_xor(s, d);
        float inv = 1.f / s;
        float4 a; a.x = e0 * inv; a.y = e1 * inv; a.z = e2 * inv; a.w = e3 * inv;
        *(float4*)&s_s[nh * NPATCH + lane * 4] = a;
        float4 r4 = *(float4*)&rstd_s[lane * 4];
        float4 wv; wv.x = a.x * r4.x; wv.y = a.y * r4.y; wv.z = a.z * r4.z; wv.w = a.w * r4.w;
        *(float4*)(ws + OFF_W + (size_t)(bt * NH16 + nh) * NPATCH + lane * 4) = wv;
    }
    __syncthreads();
    for (int r = 0; r < 4; ++r) {
        const int nh = wave * 4 + r;
        float4 a4 = *(float4*)&s_s[nh * NPATCH + lane * 4];
        float4 m4 = *(float4*)&mrs[lane * 4];
        float dd = a4.x * m4.x + a4.y * m4.y + a4.z * m4.z + a4.w * m4.w;
        for (int d = 1; d < 64; d <<= 1) dd += __shfl_xor(dd, d);
        if (lane == 0) ws[OFF_CV + bt * NH16 + nh] = dd;
    }
    #pragma unroll
    for (int n = 0; n < NB; ++n)
        aavg[n * NPATCH + t] = 0.25f * (s_s[(n * 4 + 0) * NPATCH + t] + s_s[(n * 4 + 1) * NPATCH + t]
                                      + s_s[(n * 4 + 2) * NPATCH + t] + s_s[(n * 4 + 3) * NPATCH + t]);
    __syncthreads();
    if (wave == 0) {
        float nrm[NB];
        #pragma unroll
        for (int n = 0; n < NB; ++n) {
            float4 v = *(float4*)&aavg[n * NPATCH + lane * 4];
            float ss = v.x * v.x + v.y * v.y + v.z * v.z + v.w * v.w;
            for (int d = 1; d < 64; d <<= 1) ss += __shfl_xor(ss, d);
            nrm[n] = fmaxf(sqrtf(ss), 1e-8f);
        }
        int pi = 0;
        for (int i = 0; i < NB; ++i)
            for (int j = i + 1; j < NB; ++j) {
                float4 va = *(float4*)&aavg[i * NPATCH + lane * 4];
                float4 vb = *(float4*)&aavg[j * NPATCH + lane * 4];
                float dd = va.x * vb.x + va.y * vb.y + va.z * vb.z + va.w * vb.w;
                for (int d = 1; d < 64; d <<= 1) dd += __shfl_xor(dd, d);
                if (lane == 0) ws[OFF_DIV + bt * 6 + pi] = dd / (nrm[i] * nrm[j]);
                ++pi;
            }
    }
}

// ---- C: zraw quarter-slices = sum_p w[nh,p]*x[bt,p,:] ; grid (128,4) ----
__global__ __launch_bounds__(256) void kC(const float* __restrict__ x,
                                          float* __restrict__ ws) {
    const int bt = blockIdx.x;
    const int qq = blockIdx.y;             // p-quarter
    const int t = threadIdx.x;             // dim group d0 = t*4
    __shared__ __attribute__((aligned(16))) float w_s[64 * 16];
    for (int idx = t; idx < 1024; idx += 256) {
        int p = idx >> 4, nh = idx & 15;
        w_s[idx] = ws[OFF_W + (size_t)(bt * NH16 + nh) * NPATCH + qq * 64 + p];
    }
    float4 acc[16];
    #pragma unroll
    for (int i = 0; i < 16; ++i) { acc[i].x = 0.f; acc[i].y = 0.f; acc[i].z = 0.f; acc[i].w = 0.f; }
    __syncthreads();
    const float* xp = x + (size_t)(bt * NPATCH + qq * 64) * DV + t * 4;
    #pragma unroll 4
    for (int p = 0; p < 64; ++p) {
        float4 xv = *(const float4*)(xp + (size_t)p * DV);
        float4 a0 = *(const float4*)&w_s[p * 16 + 0];
        float4 a1 = *(const float4*)&w_s[p * 16 + 4];
        float4 a2 = *(const float4*)&w_s[p * 16 + 8];
        float4 a3 = *(const float4*)&w_s[p * 16 + 12];
        #define FMA4(k, wgt) acc[k].x += (wgt) * xv.x; acc[k].y += (wgt) * xv.y; \
                             acc[k].z += (wgt) * xv.z; acc[k].w += (wgt) * xv.w;
        FMA4(0, a0.x)  FMA4(1, a0.y)  FMA4(2, a0.z)  FMA4(3, a0.w)
        FMA4(4, a1.x)  FMA4(5, a1.y)  FMA4(6, a1.z)  FMA4(7, a1.w)
        FMA4(8, a2.x)  FMA4(9, a2.y)  FMA4(10, a2.z) FMA4(11, a2.w)
        FMA4(12, a3.x) FMA4(13, a3.y) FMA4(14, a3.z) FMA4(15, a3.w)
        #undef FMA4
    }
    #pragma unroll
    for (int nh = 0; nh < 16; ++nh)
        *(float4*)(ws + OFF_XBAR + (size_t)qq * XSLICE
                   + ((size_t)bt * NH16 + nh) * DV + t * 4) = acc[nh];
}

// ---- D1: pooled = (zraw - CV)*g@Wv folded; grid 256 = 16 nh x 16 btg ----
__global__ __launch_bounds__(256) void kD1(const float* __restrict__ Wv,
                                           const float* __restrict__ g,
                                           const float* __restrict__ b,
                                           const float* __restrict__ bv,
                                           float* __restrict__ ws) {
    const int nh = blockIdx.x & 15, btg = blockIdx.x >> 4;
    const int n = nh >> 2, h = nh & 3;
    const int bt0 = btg * 8, cb = h * 64;
    __shared__ __attribute__((aligned(16))) float xs[8][1024];
    __shared__ __attribute__((aligned(16))) float gs[1024], bs[1024];
    __shared__ float red[4][64][10];
    const int t = threadIdx.x;
    for (int e = t; e < 2048; e += 256) {
        const int bt = e >> 8, i4 = e & 255;
        const size_t b0 = OFF_XBAR + ((size_t)(bt0 + bt) * NH16 + nh) * DV + i4 * 4;
        float4 s = {0.f, 0.f, 0.f, 0.f};
        #pragma unroll
        for (int qq = 0; qq < 4; ++qq) {
            float4 v = *(const float4*)(ws + b0 + (size_t)qq * XSLICE);
            s.x += v.x; s.y += v.y; s.z += v.z; s.w += v.w;
        }
        *(float4*)&xs[bt][i4 * 4] = s;
    }
    for (int e = t; e < 1024; e += 256) { gs[e] = g[e]; bs[e] = b[e]; }
    __syncthreads();
    const int c = t & 63, sub = t >> 6;
    float acc[8];
    #pragma unroll
    for (int l = 0; l < 8; ++l) acc[l] = 0.f;
    float gv = 0.f, bvv = 0.f;
    const float* wvp = Wv + ((size_t)n * DV + sub * 256) * DB + cb + c;
    const int ib0 = sub * 256;
    #pragma unroll 2
    for (int gidx = 0; gidx < 64; ++gidx) {
        const int ib = ib0 + gidx * 4;
        float w0 = wvp[(size_t)(gidx * 4 + 0) * DB];
        float w1 = wvp[(size_t)(gidx * 4 + 1) * DB];
        float w2 = wvp[(size_t)(gidx * 4 + 2) * DB];
        float w3 = wvp[(size_t)(gidx * 4 + 3) * DB];
        float4 g4 = *(const float4*)&gs[ib];
        float4 b4 = *(const float4*)&bs[ib];
        float q0 = g4.x * w0, q1 = g4.y * w1, q2 = g4.z * w2, q3 = g4.w * w3;
        gv  += q0 + q1 + q2 + q3;
        bvv += b4.x * w0 + b4.y * w1 + b4.z * w2 + b4.w * w3;
        #pragma unroll
        for (int l = 0; l < 8; ++l) {
            float4 xr = *(const float4*)&xs[l][ib];
            acc[l] += xr.x * q0 + xr.y * q1 + xr.z * q2 + xr.w * q3;
        }
    }
    #pragma unroll
    for (int l = 0; l < 8; ++l) red[sub][c][l] = acc[l];
    red[sub][c][8] = gv; red[sub][c][9] = bvv;
    __syncthreads();
    const int c2 = t & 63, l0 = t >> 6;
    float gvS = red[0][c2][8] + red[1][c2][8] + red[2][c2][8] + red[3][c2][8];
    float bvS = red[0][c2][9] + red[1][c2][9] + red[2][c2][9] + red[3][c2][9];
    float base = bv[n * DB + cb + c2] + bvS;
    #pragma unroll
    for (int li = 0; li < 2; ++li) {
        const int l = l0 + li * 4;
        float p = red[0][c2][l] + red[1][c2][l] + red[2][c2][l] + red[3][c2][l];
        float C = ws[OFF_CV + (bt0 + l) * NH16 + nh];
        ws[OFF_POOL + ((size_t)n * BT + bt0 + l) * DB + cb + c2] = p - C * gvS + base;
    }
}

// ---- D2: out = pooled @ Wo + bo ; block 0 also finalizes diversity loss ----
__global__ __launch_bounds__(256) void kD2(const float* __restrict__ Wo,
                                           const float* __restrict__ bo,
                                           const float* __restrict__ ws,
                                           float* __restrict__ out) {
    const int btg = blockIdx.x & 15, jq = (blockIdx.x >> 4) & 3, n = blockIdx.x >> 6;
    const int bt0 = btg * 8, j0 = jq * 64;
    __shared__ __attribute__((aligned(16))) float ps[8][256];
    __shared__ float red[4][64][8];
    __shared__ float dred[4];
    const int t = threadIdx.x;
    for (int e = t; e < 512; e += 256) {
        const int bt = e >> 6, c4 = e & 63;
        *(float4*)&ps[bt][c4 * 4] =
            *(const float4*)(ws + OFF_POOL + ((size_t)n * BT + bt0 + bt) * DB + c4 * 4);
    }
    float dacc = 0.f;
    if (blockIdx.x == 0)
        for (int idx = t; idx < 768; idx += 256) dacc += ws[OFF_DIV + idx];
    for (int d = 1; d < 64; d <<= 1) dacc += __shfl_xor(dacc, d);
    if ((t & 63) == 0) dred[t >> 6] = dacc;
    __syncthreads();
    if (blockIdx.x == 0 && t == 0)
        out[131072] = 0.1f * (dred[0] + dred[1] + dred[2] + dred[3]) / 768.f;
    const int j = t & 63, sub = t >> 6;
    float acc[8];
    #pragma unroll
    for (int l = 0; l < 8; ++l) acc[l] = 0.f;
    const float* wop = Wo + ((size_t)n * DB + sub * 64) * DB + j0 + j;
    const int cb0 = sub * 64;
    #pragma unroll 2
    for (int gidx = 0; gidx < 16; ++gidx) {
        const int cb = cb0 + gidx * 4;
        float w0 = wop[(size_t)(gidx * 4 + 0) * DB];
        float w1 = wop[(size_t)(gidx * 4 + 1) * DB];
        float w2 = wop[(size_t)(gidx * 4 + 2) * DB];
        float w3 = wop[(size_t)(gidx * 4 + 3) * DB];
        #pragma unroll
        for (int l = 0; l < 8; ++l) {
            float4 pr = *(const float4*)&ps[l][cb];
            acc[l] += pr.x * w0 + pr.y * w1 + pr.z * w2 + pr.w * w3;
        }
    }
    #pragma unroll
    for (int l = 0; l < 8; ++l) red[sub][j][l] = acc[l];
    __syncthreads();
    const int j2 = t & 63, l0 = t >> 6;
    float bov = bo[n * DB + j0 + j2];
    #pragma unroll
    for (int li = 0; li < 2; ++li) {
        const int l = l0 + li * 4;
        float o = red[0][j2][l] + red[1][j2][l] + red[2][j2][l] + red[3][j2][l] + bov;
        out[((size_t)(bt0 + l) * NB + n) * DB + j0 + j2] = o;
    }
}

extern "C" void kernel_launch(void* const* d_in, const int* in_sizes, int n_in,
                              void* d_out, int out_size, void* d_ws, size_t ws_size,
                              hipStream_t stream) {
    const float* x  = (const float*)d_in[0];
    const float* g  = (const float*)d_in[1];
    const float* b  = (const float*)d_in[2];
    const float* q  = (const float*)d_in[3];
    const float* Wk = (const float*)d_in[4];
    const float* bk = (const float*)d_in[5];
    const float* Wv = (const float*)d_in[6];
    const float* bv = (const float*)d_in[7];
    const float* Wo = (const float*)d_in[8];
    const float* bo = (const float*)d_in[9];
    float* out = (float*)d_out;
    float* ws  = (float*)d_ws;

    hipLaunchKernelGGL(kP,  dim3(256),    dim3(256),  0, stream, Wk, q, g, b, ws);
    hipLaunchKernelGGL(kP2, dim3(17),     dim3(1024), 0, stream, q, bk, ws);
    hipLaunchKernelGGL(kA,  dim3(512),    dim3(256),  0, stream, x, ws);
    hipLaunchKernelGGL(kB,  dim3(128),    dim3(256),  0, stream, ws);
    hipLaunchKernelGGL(kC,  dim3(128, 4), dim3(256),  0, stream, x, ws);
    hipLaunchKernelGGL(kD1, dim3(256),    dim3(256),  0, stream, Wv, g, b, bv, ws);
    hipLaunchKernelGGL(kD2, dim3(256),    dim3(256),  0, stream, Wo, bo, ws, out);
}

// Round 5
// 291.310 us; speedup vs baseline: 1.0383x; 1.0383x over previous
//
#include <hip/hip_runtime.h>
#include <stdint.h>

#define BT      128
#define NPATCH  256
#define DV      1024
#define NB      4
#define DB      256
#define NH16    16
#define SCALE   0.125f
#define LNEPS   1e-5f

// ---- ws layout (float element offsets), total ~38.7 MB ----
#define OFF_GWQ    0u          // 16*1024
#define OFF_BWS    16384u      // 16384 bf16 = 8192 floats
#define OFF_S      24576u      // 16
#define OFF_CB     24592u      // 16
#define OFF_PSC    24608u      // 512
#define OFF_DRAW   25120u      // 32768*16
#define OFF_STATS  549408u     // 32768*2 (mu,rstd)
#define OFF_W      614944u     // 128*16*256 (attn*rstd)
#define OFF_CV     1139232u    // 128*16
#define OFF_DIV    1141280u    // 768
#define OFF_XBAR   1142048u    // 4 slices * 2097152
#define OFF_POOL   9530656u    // 4*128*256
#define XSLICE     2097152u

#define LROW 264               // bf16 per LDS row (256 + 8 pad)

typedef short bf16x8 __attribute__((ext_vector_type(8)));
typedef float f32x4  __attribute__((ext_vector_type(4)));

__device__ __forceinline__ short f2bf(float f) {   // RNE
    union { float f; unsigned u; } v; v.f = f;
    unsigned u = v.u;
    unsigned r = (u + 0x7fffu + ((u >> 16) & 1u)) >> 16;
    return (short)r;
}

// pack two floats -> two truncated bf16 in one v_perm_b32
__device__ __forceinline__ unsigned pk2(float lo, float hi) {
    union { float f; unsigned u; } a, b; a.f = lo; b.f = hi;
    return __builtin_amdgcn_perm(b.u, a.u, 0x07060302u);
}

// ---- P: partial wq dots, 256 blocks = 16 nh x 16 i-chunks of 64 rows ----
__global__ __launch_bounds__(256) void kP(const float* __restrict__ Wk,
                                          const float* __restrict__ q,
                                          const float* __restrict__ g,
                                          const float* __restrict__ b,
                                          float* __restrict__ ws) {
    const int nh = blockIdx.x >> 4, ich = blockIdx.x & 15;
    const int n = nh >> 2, h = nh & 3;
    __shared__ float qs[64];
    __shared__ float redS[4], redC[4];
    const int t = threadIdx.x;
    if (t < 64) qs[t] = q[nh * 64 + t];
    __syncthreads();
    const int r = t >> 2, qd = t & 3;
    const int i = ich * 64 + r;
    const float* wrow = Wk + ((size_t)n * DV + i) * DB + h * 64 + qd * 16;
    float acc = 0.f;
    #pragma unroll
    for (int d = 0; d < 16; d += 4) {
        float4 w4 = *(const float4*)(wrow + d);
        acc += w4.x * qs[qd * 16 + d]     + w4.y * qs[qd * 16 + d + 1]
             + w4.z * qs[qd * 16 + d + 2] + w4.w * qs[qd * 16 + d + 3];
    }
    acc += __shfl_xor(acc, 1);
    acc += __shfl_xor(acc, 2);
    float gw = g[i] * acc;
    if (qd == 0) ws[OFF_GWQ + nh * DV + i] = gw;
    float mS = (qd == 0) ? gw : 0.f;
    float mC = (qd == 0) ? b[i] * acc : 0.f;
    #pragma unroll
    for (int dd = 4; dd < 64; dd <<= 1) { mS += __shfl_xor(mS, dd); mC += __shfl_xor(mC, dd); }
    const int wave = t >> 6, lane = t & 63;
    if (lane == 0) { redS[wave] = mS; redC[wave] = mC; }
    __syncthreads();
    if (t == 0) {
        ws[OFF_PSC + (nh * 16 + ich) * 2 + 0] = redS[0] + redS[1] + redS[2] + redS[3];
        ws[OFF_PSC + (nh * 16 + ich) * 2 + 1] = redC[0] + redC[1] + redC[2] + redC[3];
    }
}

// ---- P2: blocks 0..15 pack B-frags; block 16 reduces S/Cb ----
__global__ __launch_bounds__(1024) void kP2(const float* __restrict__ q,
                                            const float* __restrict__ bk,
                                            float* __restrict__ ws) {
    const int blk = blockIdx.x;
    const int t = threadIdx.x;
    if (blk == 16) {
        if (t < 16) {
            const int nh = t, n = nh >> 2, h = nh & 3;
            float S = 0.f, C = 0.f;
            for (int ich = 0; ich < 16; ++ich) {
                S += ws[OFF_PSC + (nh * 16 + ich) * 2 + 0];
                C += ws[OFF_PSC + (nh * 16 + ich) * 2 + 1];
            }
            float bkq = 0.f;
            for (int d = 0; d < 64; ++d) bkq += bk[n * DB + h * 64 + d] * q[nh * 64 + d];
            ws[OFF_S + nh]  = S;
            ws[OFF_CB + nh] = C + bkq;
        }
        return;
    }
    unsigned short* bws = (unsigned short*)(ws + OFF_BWS);
    const float* gwq = ws + OFF_GWQ;
    const int idx = blk * 1024 + t;
    const int j = idx & 7, lane = (idx >> 3) & 63, kt = idx >> 9;
    const int nh = lane & 15;
    const int k = kt * 32 + ((lane >> 4) * 8) + j;
    bws[idx] = (unsigned short)f2bf(gwq[nh * DV + k]);
}

// ---- A: single-buffer LDS + register prefetch; 512 blocks x 64 rows ----
// 33.8 KB LDS -> 4 blocks/CU; loads for chunk c+1 in flight during MFMA(c)
__global__ __launch_bounds__(256) void kA(const float* __restrict__ x,
                                          float* __restrict__ ws) {
    __shared__ unsigned short xs[64 * LROW];
    const int t = threadIdx.x;
    const int wv = t >> 6, lane = t & 63;
    const int m = lane & 15, oct = lane >> 4;
    const int row0 = blockIdx.x * 64;
    const bf16x8* bfp = (const bf16x8*)((const unsigned short*)(ws + OFF_BWS));
    const float* xb = x + (size_t)row0 * DV;

    float sum[16], sq[16];
    #pragma unroll
    for (int i = 0; i < 16; ++i) { sum[i] = 0.f; sq[i] = 0.f; }
    f32x4 acc = {0.f, 0.f, 0.f, 0.f};
    float4 r[16];

    auto loadr = [&](int c) {
        #pragma unroll
        for (int i = 0; i < 16; ++i)
            r[i] = *(const float4*)(xb + (size_t)(i * 4 + wv) * DV + c * 256 + lane * 4);
    };
    auto commit = [&]() {
        #pragma unroll
        for (int i = 0; i < 16; ++i) {
            float4 v = r[i];
            sum[i] += v.x + v.y + v.z + v.w;
            sq[i]  += v.x * v.x + v.y * v.y + v.z * v.z + v.w * v.w;
            uint2 pk; pk.x = pk2(v.x, v.y); pk.y = pk2(v.z, v.w);
            *(uint2*)&xs[(i * 4 + wv) * LROW + lane * 4] = pk;
        }
    };
    auto comp = [&](int c) {
        #pragma unroll
        for (int kt = 0; kt < 8; ++kt) {
            bf16x8 af = *(const bf16x8*)&xs[(wv * 16 + m) * LROW + kt * 32 + oct * 8];
            bf16x8 bf = bfp[(c * 8 + kt) * 64 + lane];
            acc = __builtin_amdgcn_mfma_f32_16x16x32_bf16(af, bf, acc, 0, 0, 0);
        }
    };

    loadr(0);
    for (int c = 0; c < 4; ++c) {
        __syncthreads();          // prior chunk's LDS reads done
        commit();                 // regs -> LDS (+ LN sums)
        __syncthreads();
        if (c < 3) loadr(c + 1);  // next chunk's global loads in flight
        comp(c);                  // MFMA from LDS
    }

    // raw dots: C-layout col=lane&15 (nh), row=(lane>>4)*4+r within wave tile
    #pragma unroll
    for (int r2 = 0; r2 < 4; ++r2)
        ws[OFF_DRAW + (size_t)(row0 + wv * 16 + oct * 4 + r2) * 16 + m] = acc[r2];

    // LN stats: row i*4+wv partials live across this wave's 64 lanes
    #pragma unroll
    for (int i = 0; i < 16; ++i) {
        float s = sum[i], q2 = sq[i];
        #pragma unroll
        for (int d = 1; d < 64; d <<= 1) { s += __shfl_xor(s, d); q2 += __shfl_xor(q2, d); }
        if (lane == 0) {
            const int row = row0 + i * 4 + wv;
            const float mu  = s * (1.f / 1024.f);
            const float var = q2 * (1.f / 1024.f) - mu * mu;
            float2 st; st.x = mu; st.y = rsqrtf(var + LNEPS);
            *(float2*)(ws + OFF_STATS + (size_t)row * 2) = st;
        }
    }
}

// ---- B: scores -> softmax -> W=attn*rstd, CV, diversity ----
__global__ __launch_bounds__(256) void kB(float* __restrict__ ws) {
    const int bt = blockIdx.x;
    const int t = threadIdx.x;            // patch p
    __shared__ __attribute__((aligned(16))) float s_s[NH16 * NPATCH];
    __shared__ __attribute__((aligned(16))) float aavg[NB * NPATCH];
    __shared__ __attribute__((aligned(16))) float rstd_s[NPATCH];
    __shared__ __attribute__((aligned(16))) float mrs[NPATCH];
    __shared__ float Ss[NH16], Cbs[NH16];
    if (t < NH16) Ss[t] = ws[OFF_S + t];
    else if (t < 32) Cbs[t - 16] = ws[OFF_CB + (t - 16)];
    const size_t row = (size_t)bt * NPATCH + t;
    const float2 st = *(const float2*)(ws + OFF_STATS + row * 2);
    const float mu = st.x, rstd = st.y;
    rstd_s[t] = rstd;
    mrs[t] = mu * rstd;
    __syncthreads();
    const float* dr = ws + OFF_DRAW + row * 16;
    #pragma unroll
    for (int nh = 0; nh < NH16; ++nh) {
        float D = dr[nh];
        s_s[nh * NPATCH + t] = (rstd * (D - mu * Ss[nh]) + Cbs[nh]) * SCALE;
    }
    __syncthreads();
    const int wave = t >> 6, lane = t & 63;
    for (int r = 0; r < 4; ++r) {
        const int nh = wave * 4 + r;
        float4 v = *(float4*)&s_s[nh * NPATCH + lane * 4];
        float mx = fmaxf(fmaxf(v.x, v.y), fmaxf(v.z, v.w));
        for (int d = 1; d < 64; d <<= 1) mx = fmaxf(mx, __shfl_xor(mx, d));
        float e0 = __expf(v.x - mx), e1 = __expf(v.y - mx);
        float e2 = __expf(v.z - mx), e3 = __expf(v.w - mx);
        float s = e0 + e1 + e2 + e3;
        for (int d = 1; d < 64; d <<= 1) s += __shfl_xor(s, d);
        float inv = 1.f / s;
        float4 a; a.x = e0 * inv; a.y = e1 * inv; a.z = e2 * inv; a.w = e3 * inv;
        *(float4*)&s_s[nh * NPATCH + lane * 4] = a;
        float4 r4 = *(float4*)&rstd_s[lane * 4];
        float4 wv; wv.x = a.x * r4.x; wv.y = a.y * r4.y; wv.z = a.z * r4.z; wv.w = a.w * r4.w;
        *(float4*)(ws + OFF_W + (size_t)(bt * NH16 + nh) * NPATCH + lane * 4) = wv;
    }
    __syncthreads();
    for (int r = 0; r < 4; ++r) {
        const int nh = wave * 4 + r;
        float4 a4 = *(float4*)&s_s[nh * NPATCH + lane * 4];
        float4 m4 = *(float4*)&mrs[lane * 4];
        float dd = a4.x * m4.x + a4.y * m4.y + a4.z * m4.z + a4.w * m4.w;
        for (int d = 1; d < 64; d <<= 1) dd += __shfl_xor(dd, d);
        if (lane == 0) ws[OFF_CV + bt * NH16 + nh] = dd;
    }
    #pragma unroll
    for (int n = 0; n < NB; ++n)
        aavg[n * NPATCH + t] = 0.25f * (s_s[(n * 4 + 0) * NPATCH + t] + s_s[(n * 4 + 1) * NPATCH + t]
                                      + s_s[(n * 4 + 2) * NPATCH + t] + s_s[(n * 4 + 3) * NPATCH + t]);
    __syncthreads();
    if (wave == 0) {
        float nrm[NB];
        #pragma unroll
        for (int n = 0; n < NB; ++n) {
            float4 v = *(float4*)&aavg[n * NPATCH + lane * 4];
            float ss = v.x * v.x + v.y * v.y + v.z * v.z + v.w * v.w;
            for (int d = 1; d < 64; d <<= 1) ss += __shfl_xor(ss, d);
            nrm[n] = fmaxf(sqrtf(ss), 1e-8f);
        }
        int pi = 0;
        for (int i = 0; i < NB; ++i)
            for (int j = i + 1; j < NB; ++j) {
                float4 va = *(float4*)&aavg[i * NPATCH + lane * 4];
                float4 vb = *(float4*)&aavg[j * NPATCH + lane * 4];
                float dd = va.x * vb.x + va.y * vb.y + va.z * vb.z + va.w * vb.w;
                for (int d = 1; d < 64; d <<= 1) dd += __shfl_xor(dd, d);
                if (lane == 0) ws[OFF_DIV + bt * 6 + pi] = dd / (nrm[i] * nrm[j]);
                ++pi;
            }
    }
}

// ---- C: zraw quarter-slices; 4-way p-interleaved loads for MLP ----
__global__ __launch_bounds__(256) void kC(const float* __restrict__ x,
                                          float* __restrict__ ws) {
    const int bt = blockIdx.x;
    const int qq = blockIdx.y;             // p-quarter
    const int t = threadIdx.x;             // dim group d0 = t*4
    __shared__ __attribute__((aligned(16))) float w_s[64 * 16];
    for (int idx = t; idx < 1024; idx += 256) {
        int p = idx >> 4, nh = idx & 15;
        w_s[idx] = ws[OFF_W + (size_t)(bt * NH16 + nh) * NPATCH + qq * 64 + p];
    }
    float4 acc[16];
    #pragma unroll
    for (int i = 0; i < 16; ++i) { acc[i].x = 0.f; acc[i].y = 0.f; acc[i].z = 0.f; acc[i].w = 0.f; }
    __syncthreads();
    const float* xp = x + (size_t)(bt * NPATCH + qq * 64) * DV + t * 4;
    #define FMA4(k, wgt, xv) acc[k].x += (wgt) * xv.x; acc[k].y += (wgt) * xv.y; \
                             acc[k].z += (wgt) * xv.z; acc[k].w += (wgt) * xv.w;
    #define PBLOCK(p, xv) { \
        float4 a0 = *(const float4*)&w_s[(p) * 16 + 0]; \
        float4 a1 = *(const float4*)&w_s[(p) * 16 + 4]; \
        float4 a2 = *(const float4*)&w_s[(p) * 16 + 8]; \
        float4 a3 = *(const float4*)&w_s[(p) * 16 + 12]; \
        FMA4(0, a0.x, xv)  FMA4(1, a0.y, xv)  FMA4(2, a0.z, xv)  FMA4(3, a0.w, xv) \
        FMA4(4, a1.x, xv)  FMA4(5, a1.y, xv)  FMA4(6, a1.z, xv)  FMA4(7, a1.w, xv) \
        FMA4(8, a2.x, xv)  FMA4(9, a2.y, xv)  FMA4(10, a2.z, xv) FMA4(11, a2.w, xv) \
        FMA4(12, a3.x, xv) FMA4(13, a3.y, xv) FMA4(14, a3.z, xv) FMA4(15, a3.w, xv) }
    for (int p = 0; p < 16; ++p) {
        float4 xv0 = *(const float4*)(xp + (size_t)(p +  0) * DV);
        float4 xv1 = *(const float4*)(xp + (size_t)(p + 16) * DV);
        float4 xv2 = *(const float4*)(xp + (size_t)(p + 32) * DV);
        float4 xv3 = *(const float4*)(xp + (size_t)(p + 48) * DV);
        PBLOCK(p, xv0)
        PBLOCK(p + 16, xv1)
        PBLOCK(p + 32, xv2)
        PBLOCK(p + 48, xv3)
    }
    #undef PBLOCK
    #undef FMA4
    #pragma unroll
    for (int nh = 0; nh < 16; ++nh)
        *(float4*)(ws + OFF_XBAR + (size_t)qq * XSLICE
                   + ((size_t)bt * NH16 + nh) * DV + t * 4) = acc[nh];
}

// ---- D1: pooled = (zraw - CV)*g@Wv folded; grid 256 = 16 nh x 16 btg ----
__global__ __launch_bounds__(256) void kD1(const float* __restrict__ Wv,
                                           const float* __restrict__ g,
                                           const float* __restrict__ b,
                                           const float* __restrict__ bv,
                                           float* __restrict__ ws) {
    const int nh = blockIdx.x & 15, btg = blockIdx.x >> 4;
    const int n = nh >> 2, h = nh & 3;
    const int bt0 = btg * 8, cb = h * 64;
    __shared__ __attribute__((aligned(16))) float xs[8][1024];
    __shared__ __attribute__((aligned(16))) float gs[1024], bs[1024];
    __shared__ float red[4][64][10];
    const int t = threadIdx.x;
    for (int e = t; e < 2048; e += 256) {
        const int bt = e >> 8, i4 = e & 255;
        const size_t b0 = OFF_XBAR + ((size_t)(bt0 + bt) * NH16 + nh) * DV + i4 * 4;
        float4 s = {0.f, 0.f, 0.f, 0.f};
        #pragma unroll
        for (int qq = 0; qq < 4; ++qq) {
            float4 v = *(const float4*)(ws + b0 + (size_t)qq * XSLICE);
            s.x += v.x; s.y += v.y; s.z += v.z; s.w += v.w;
        }
        *(float4*)&xs[bt][i4 * 4] = s;
    }
    for (int e = t; e < 1024; e += 256) { gs[e] = g[e]; bs[e] = b[e]; }
    __syncthreads();
    const int c = t & 63, sub = t >> 6;
    float acc[8];
    #pragma unroll
    for (int l = 0; l < 8; ++l) acc[l] = 0.f;
    float gv = 0.f, bvv = 0.f;
    const float* wvp = Wv + ((size_t)n * DV + sub * 256) * DB + cb + c;
    const int ib0 = sub * 256;
    #pragma unroll 2
    for (int gidx = 0; gidx < 64; ++gidx) {
        const int ib = ib0 + gidx * 4;
        float w0 = wvp[(size_t)(gidx * 4 + 0) * DB];
        float w1 = wvp[(size_t)(gidx * 4 + 1) * DB];
        float w2 = wvp[(size_t)(gidx * 4 + 2) * DB];
        float w3 = wvp[(size_t)(gidx * 4 + 3) * DB];
        float4 g4 = *(const float4*)&gs[ib];
        float4 b4 = *(const float4*)&bs[ib];
        float q0 = g4.x * w0, q1 = g4.y * w1, q2 = g4.z * w2, q3 = g4.w * w3;
        gv  += q0 + q1 + q2 + q3;
        bvv += b4.x * w0 + b4.y * w1 + b4.z * w2 + b4.w * w3;
        #pragma unroll
        for (int l = 0; l < 8; ++l) {
            float4 xr = *(const float4*)&xs[l][ib];
            acc[l] += xr.x * q0 + xr.y * q1 + xr.z * q2 + xr.w * q3;
        }
    }
    #pragma unroll
    for (int l = 0; l < 8; ++l) red[sub][c][l] = acc[l];
    red[sub][c][8] = gv; red[sub][c][9] = bvv;
    __syncthreads();
    const int c2 = t & 63, l0 = t >> 6;
    float gvS = red[0][c2][8] + red[1][c2][8] + red[2][c2][8] + red[3][c2][8];
    float bvS = red[0][c2][9] + red[1][c2][9] + red[2][c2][9] + red[3][c2][9];
    float base = bv[n * DB + cb + c2] + bvS;
    #pragma unroll
    for (int li = 0; li < 2; ++li) {
        const int l = l0 + li * 4;
        float p = red[0][c2][l] + red[1][c2][l] + red[2][c2][l] + red[3][c2][l];
        float C = ws[OFF_CV + (bt0 + l) * NH16 + nh];
        ws[OFF_POOL + ((size_t)n * BT + bt0 + l) * DB + cb + c2] = p - C * gvS + base;
    }
}

// ---- D2: out = pooled @ Wo + bo ; block 0 also finalizes diversity loss ----
__global__ __launch_bounds__(256) void kD2(const float* __restrict__ Wo,
                                           const float* __restrict__ bo,
                                           const float* __restrict__ ws,
                                           float* __restrict__ out) {
    const int btg = blockIdx.x & 15, jq = (blockIdx.x >> 4) & 3, n = blockIdx.x >> 6;
    const int bt0 = btg * 8, j0 = jq * 64;
    __shared__ __attribute__((aligned(16))) float ps[8][256];
    __shared__ float red[4][64][8];
    __shared__ float dred[4];
    const int t = threadIdx.x;
    for (int e = t; e < 512; e += 256) {
        const int bt = e >> 6, c4 = e & 63;
        *(float4*)&ps[bt][c4 * 4] =
            *(const float4*)(ws + OFF_POOL + ((size_t)n * BT + bt0 + bt) * DB + c4 * 4);
    }
    float dacc = 0.f;
    if (blockIdx.x == 0)
        for (int idx = t; idx < 768; idx += 256) dacc += ws[OFF_DIV + idx];
    for (int d = 1; d < 64; d <<= 1) dacc += __shfl_xor(dacc, d);
    if ((t & 63) == 0) dred[t >> 6] = dacc;
    __syncthreads();
    if (blockIdx.x == 0 && t == 0)
        out[131072] = 0.1f * (dred[0] + dred[1] + dred[2] + dred[3]) / 768.f;
    const int j = t & 63, sub = t >> 6;
    float acc[8];
    #pragma unroll
    for (int l = 0; l < 8; ++l) acc[l] = 0.f;
    const float* wop = Wo + ((size_t)n * DB + sub * 64) * DB + j0 + j;
    const int cb0 = sub * 64;
    #pragma unroll 2
    for (int gidx = 0; gidx < 16; ++gidx) {
        const int cb = cb0 + gidx * 4;
        float w0 = wop[(size_t)(gidx * 4 + 0) * DB];
        float w1 = wop[(size_t)(gidx * 4 + 1) * DB];
        float w2 = wop[(size_t)(gidx * 4 + 2) * DB];
        float w3 = wop[(size_t)(gidx * 4 + 3) * DB];
        #pragma unroll
        for (int l = 0; l < 8; ++l) {
            float4 pr = *(const float4*)&ps[l][cb];
            acc[l] += pr.x * w0 + pr.y * w1 + pr.z * w2 + pr.w * w3;
        }
    }
    #pragma unroll
    for (int l = 0; l < 8; ++l) red[sub][j][l] = acc[l];
    __syncthreads();
    const int j2 = t & 63, l0 = t >> 6;
    float bov = bo[n * DB + j0 + j2];
    #pragma unroll
    for (int li = 0; li < 2; ++li) {
        const int l = l0 + li * 4;
        float o = red[0][j2][l] + red[1][j2][l] + red[2][j2][l] + red[3][j2][l] + bov;
        out[((size_t)(bt0 + l) * NB + n) * DB + j0 + j2] = o;
    }
}

extern "C" void kernel_launch(void* const* d_in, const int* in_sizes, int n_in,
                              void* d_out, int out_size, void* d_ws, size_t ws_size,
                              hipStream_t stream) {
    const float* x  = (const float*)d_in[0];
    const float* g  = (const float*)d_in[1];
    const float* b  = (const float*)d_in[2];
    const float* q  = (const float*)d_in[3];
    const float* Wk = (const float*)d_in[4];
    const float* bk = (const float*)d_in[5];
    const float* Wv = (const float*)d_in[6];
    const float* bv = (const float*)d_in[7];
    const float* Wo = (const float*)d_in[8];
    const float* bo = (const float*)d_in[9];
    float* out = (float*)d_out;
    float* ws  = (float*)d_ws;

    hipLaunchKernelGGL(kP,  dim3(256),    dim3(256),  0, stream, Wk, q, g, b, ws);
    hipLaunchKernelGGL(kP2, dim3(17),     dim3(1024), 0, stream, q, bk, ws);
    hipLaunchKernelGGL(kA,  dim3(512),    dim3(256),  0, stream, x, ws);
    hipLaunchKernelGGL(kB,  dim3(128),    dim3(256),  0, stream, ws);
    hipLaunchKernelGGL(kC,  dim3(128, 4), dim3(256),  0, stream, x, ws);
    hipLaunchKernelGGL(kD1, dim3(256),    dim3(256),  0, stream, Wv, g, b, bv, ws);
    hipLaunchKernelGGL(kD2, dim3(256),    dim3(256),  0, stream, Wo, bo, ws, out);
}

// Round 6
// 286.779 us; speedup vs baseline: 1.0547x; 1.0158x over previous
//
#include <hip/hip_runtime.h>
#include <stdint.h>

#define BT      128
#define NPATCH  256
#define DV      1024
#define NB      4
#define DB      256
#define NH16    16
#define SCALE   0.125f
#define LNEPS   1e-5f

// ---- ws layout (float element offsets), total ~38.7 MB ----
#define OFF_BWS    16384u      // 16384 bf16 = 8192 floats (MFMA B-frags)
#define OFF_PSC    24608u      // 16 nh * 16 ich * 2 partial S/C
#define OFF_DRAW   25120u      // 32768*16
#define OFF_STATS  549408u     // 32768*2 (mu,rstd)
#define OFF_W      614944u     // 128*16*256 (attn*rstd)
#define OFF_CV     1139232u    // 128*16
#define OFF_DIV    1141280u    // 768
#define OFF_XBAR   1142048u    // 4 slices * 2097152
#define OFF_POOL   9530656u    // 4*128*256
#define XSLICE     2097152u

#define LROW 264               // bf16 per LDS row (256 + 8 pad)

typedef short bf16x8 __attribute__((ext_vector_type(8)));
typedef float f32x4  __attribute__((ext_vector_type(4)));

__device__ __forceinline__ short f2bf(float f) {   // RNE
    union { float f; unsigned u; } v; v.f = f;
    unsigned u = v.u;
    unsigned r = (u + 0x7fffu + ((u >> 16) & 1u)) >> 16;
    return (short)r;
}

// pack two floats -> two truncated bf16 in one v_perm_b32
__device__ __forceinline__ unsigned pk2(float lo, float hi) {
    union { float f; unsigned u; } a, b; a.f = lo; b.f = hi;
    return __builtin_amdgcn_perm(b.u, a.u, 0x07060302u);
}

// ---- P: wq dots + direct bf16 B-frag pack; 256 blocks = 16 nh x 16 ich ----
// block (nh,ich) owns k in [ich*64, ich*64+64) == frag region kt in {2ich,2ich+1}
__global__ __launch_bounds__(256) void kP(const float* __restrict__ Wk,
                                          const float* __restrict__ q,
                                          const float* __restrict__ g,
                                          const float* __restrict__ b,
                                          float* __restrict__ ws) {
    const int nh = blockIdx.x >> 4, ich = blockIdx.x & 15;
    const int n = nh >> 2, h = nh & 3;
    __shared__ float qs[64];
    __shared__ float redS[4], redC[4];
    const int t = threadIdx.x;
    if (t < 64) qs[t] = q[nh * 64 + t];
    __syncthreads();
    const int r = t >> 2, qd = t & 3;
    const int i = ich * 64 + r;
    const float* wrow = Wk + ((size_t)n * DV + i) * DB + h * 64 + qd * 16;
    float acc = 0.f;
    #pragma unroll
    for (int d = 0; d < 16; d += 4) {
        float4 w4 = *(const float4*)(wrow + d);
        acc += w4.x * qs[qd * 16 + d]     + w4.y * qs[qd * 16 + d + 1]
             + w4.z * qs[qd * 16 + d + 2] + w4.w * qs[qd * 16 + d + 3];
    }
    acc += __shfl_xor(acc, 1);
    acc += __shfl_xor(acc, 2);             // full 64-d dot in all 4 qd lanes
    float gw = g[i] * acc;
    if (qd == 0) {
        // B-frag: bws[(kt*64 + oct*16 + nh)*8 + j], kt=i>>5, oct=(r>>3)&3, j=r&7
        unsigned short* bws = (unsigned short*)(ws + OFF_BWS);
        const int kt = i >> 5, oct = (r >> 3) & 3, j = r & 7;
        bws[((kt * 64 + oct * 16 + nh) << 3) + j] = (unsigned short)f2bf(gw);
    }
    float mS = (qd == 0) ? gw : 0.f;
    float mC = (qd == 0) ? b[i] * acc : 0.f;
    #pragma unroll
    for (int dd = 4; dd < 64; dd <<= 1) { mS += __shfl_xor(mS, dd); mC += __shfl_xor(mC, dd); }
    const int wave = t >> 6, lane = t & 63;
    if (lane == 0) { redS[wave] = mS; redC[wave] = mC; }
    __syncthreads();
    if (t == 0) {
        ws[OFF_PSC + (nh * 16 + ich) * 2 + 0] = redS[0] + redS[1] + redS[2] + redS[3];
        ws[OFF_PSC + (nh * 16 + ich) * 2 + 1] = redC[0] + redC[1] + redC[2] + redC[3];
    }
}

// ---- A: single-buffer LDS + register prefetch; 512 blocks x 64 rows ----
// 33.8 KB LDS -> 4 blocks/CU; loads for chunk c+1 in flight during MFMA(c)
__global__ __launch_bounds__(256) void kA(const float* __restrict__ x,
                                          float* __restrict__ ws) {
    __shared__ unsigned short xs[64 * LROW];
    const int t = threadIdx.x;
    const int wv = t >> 6, lane = t & 63;
    const int m = lane & 15, oct = lane >> 4;
    const int row0 = blockIdx.x * 64;
    const bf16x8* bfp = (const bf16x8*)((const unsigned short*)(ws + OFF_BWS));
    const float* xb = x + (size_t)row0 * DV;

    float sum[16], sq[16];
    #pragma unroll
    for (int i = 0; i < 16; ++i) { sum[i] = 0.f; sq[i] = 0.f; }
    f32x4 acc = {0.f, 0.f, 0.f, 0.f};
    float4 r[16];

    auto loadr = [&](int c) {
        #pragma unroll
        for (int i = 0; i < 16; ++i)
            r[i] = *(const float4*)(xb + (size_t)(i * 4 + wv) * DV + c * 256 + lane * 4);
    };
    auto commit = [&]() {
        #pragma unroll
        for (int i = 0; i < 16; ++i) {
            float4 v = r[i];
            sum[i] += v.x + v.y + v.z + v.w;
            sq[i]  += v.x * v.x + v.y * v.y + v.z * v.z + v.w * v.w;
            uint2 pk; pk.x = pk2(v.x, v.y); pk.y = pk2(v.z, v.w);
            *(uint2*)&xs[(i * 4 + wv) * LROW + lane * 4] = pk;
        }
    };
    auto comp = [&](int c) {
        #pragma unroll
        for (int kt = 0; kt < 8; ++kt) {
            bf16x8 af = *(const bf16x8*)&xs[(wv * 16 + m) * LROW + kt * 32 + oct * 8];
            bf16x8 bf = bfp[(c * 8 + kt) * 64 + lane];
            acc = __builtin_amdgcn_mfma_f32_16x16x32_bf16(af, bf, acc, 0, 0, 0);
        }
    };

    loadr(0);
    for (int c = 0; c < 4; ++c) {
        __syncthreads();          // prior chunk's LDS reads done
        commit();                 // regs -> LDS (+ LN sums)
        __syncthreads();
        if (c < 3) loadr(c + 1);  // next chunk's global loads in flight
        comp(c);                  // MFMA from LDS
    }

    // raw dots: C-layout col=lane&15 (nh), row=(lane>>4)*4+r within wave tile
    #pragma unroll
    for (int r2 = 0; r2 < 4; ++r2)
        ws[OFF_DRAW + (size_t)(row0 + wv * 16 + oct * 4 + r2) * 16 + m] = acc[r2];

    // LN stats: row i*4+wv partials live across this wave's 64 lanes
    #pragma unroll
    for (int i = 0; i < 16; ++i) {
        float s = sum[i], q2 = sq[i];
        #pragma unroll
        for (int d = 1; d < 64; d <<= 1) { s += __shfl_xor(s, d); q2 += __shfl_xor(q2, d); }
        if (lane == 0) {
            const int row = row0 + i * 4 + wv;
            const float mu  = s * (1.f / 1024.f);
            const float var = q2 * (1.f / 1024.f) - mu * mu;
            float2 st; st.x = mu; st.y = rsqrtf(var + LNEPS);
            *(float2*)(ws + OFF_STATS + (size_t)row * 2) = st;
        }
    }
}

// ---- B: S/Cb reduce + scores -> softmax -> W=attn*rstd, CV, diversity ----
__global__ __launch_bounds__(256) void kB(const float* __restrict__ q,
                                          const float* __restrict__ bk,
                                          float* __restrict__ ws) {
    const int bt = blockIdx.x;
    const int t = threadIdx.x;            // patch p
    __shared__ __attribute__((aligned(16))) float s_s[NH16 * NPATCH];
    __shared__ __attribute__((aligned(16))) float aavg[NB * NPATCH];
    __shared__ __attribute__((aligned(16))) float rstd_s[NPATCH];
    __shared__ __attribute__((aligned(16))) float mrs[NPATCH];
    __shared__ float Ss[NH16], Cbs[NH16];
    if (t < NH16) {                       // per-nh S and Cb from kP partials
        const int nh2 = t, n2 = nh2 >> 2, h2 = nh2 & 3;
        float S = 0.f, C = 0.f;
        #pragma unroll
        for (int ich = 0; ich < 16; ++ich) {
            S += ws[OFF_PSC + (nh2 * 16 + ich) * 2 + 0];
            C += ws[OFF_PSC + (nh2 * 16 + ich) * 2 + 1];
        }
        float bkq = 0.f;
        #pragma unroll
        for (int d = 0; d < 64; ++d) bkq += bk[n2 * DB + h2 * 64 + d] * q[nh2 * 64 + d];
        Ss[t] = S; Cbs[t] = C + bkq;
    }
    const size_t row = (size_t)bt * NPATCH + t;
    const float2 st = *(const float2*)(ws + OFF_STATS + row * 2);
    const float mu = st.x, rstd = st.y;
    rstd_s[t] = rstd;
    mrs[t] = mu * rstd;
    __syncthreads();
    const float* dr = ws + OFF_DRAW + row * 16;
    #pragma unroll
    for (int nh = 0; nh < NH16; ++nh) {
        float D = dr[nh];
        s_s[nh * NPATCH + t] = (rstd * (D - mu * Ss[nh]) + Cbs[nh]) * SCALE;
    }
    __syncthreads();
    const int wave = t >> 6, lane = t & 63;
    for (int r = 0; r < 4; ++r) {
        const int nh = wave * 4 + r;
        float4 v = *(float4*)&s_s[nh * NPATCH + lane * 4];
        float mx = fmaxf(fmaxf(v.x, v.y), fmaxf(v.z, v.w));
        for (int d = 1; d < 64; d <<= 1) mx = fmaxf(mx, __shfl_xor(mx, d));
        float e0 = __expf(v.x - mx), e1 = __expf(v.y - mx);
        float e2 = __expf(v.z - mx), e3 = __expf(v.w - mx);
        float s = e0 + e1 + e2 + e3;
        for (int d = 1; d < 64; d <<= 1) s += __shfl_xor(s, d);
        float inv = 1.f / s;
        float4 a; a.x = e0 * inv; a.y = e1 * inv; a.z = e2 * inv; a.w = e3 * inv;
        *(float4*)&s_s[nh * NPATCH + lane * 4] = a;
        float4 r4 = *(float4*)&rstd_s[lane * 4];
        float4 wv; wv.x = a.x * r4.x; wv.y = a.y * r4.y; wv.z = a.z * r4.z; wv.w = a.w * r4.w;
        *(float4*)(ws + OFF_W + (size_t)(bt * NH16 + nh) * NPATCH + lane * 4) = wv;
    }
    __syncthreads();
    for (int r = 0; r < 4; ++r) {
        const int nh = wave * 4 + r;
        float4 a4 = *(float4*)&s_s[nh * NPATCH + lane * 4];
        float4 m4 = *(float4*)&mrs[lane * 4];
        float dd = a4.x * m4.x + a4.y * m4.y + a4.z * m4.z + a4.w * m4.w;
        for (int d = 1; d < 64; d <<= 1) dd += __shfl_xor(dd, d);
        if (lane == 0) ws[OFF_CV + bt * NH16 + nh] = dd;
    }
    #pragma unroll
    for (int n = 0; n < NB; ++n)
        aavg[n * NPATCH + t] = 0.25f * (s_s[(n * 4 + 0) * NPATCH + t] + s_s[(n * 4 + 1) * NPATCH + t]
                                      + s_s[(n * 4 + 2) * NPATCH + t] + s_s[(n * 4 + 3) * NPATCH + t]);
    __syncthreads();
    if (wave == 0) {
        float nrm[NB];
        #pragma unroll
        for (int n = 0; n < NB; ++n) {
            float4 v = *(float4*)&aavg[n * NPATCH + lane * 4];
            float ss = v.x * v.x + v.y * v.y + v.z * v.z + v.w * v.w;
            for (int d = 1; d < 64; d <<= 1) ss += __shfl_xor(ss, d);
            nrm[n] = fmaxf(sqrtf(ss), 1e-8f);
        }
        int pi = 0;
        for (int i = 0; i < NB; ++i)
            for (int j = i + 1; j < NB; ++j) {
                float4 va = *(float4*)&aavg[i * NPATCH + lane * 4];
                float4 vb = *(float4*)&aavg[j * NPATCH + lane * 4];
                float dd = va.x * vb.x + va.y * vb.y + va.z * vb.z + va.w * vb.w;
                for (int d = 1; d < 64; d <<= 1) dd += __shfl_xor(dd, d);
                if (lane == 0) ws[OFF_DIV + bt * 6 + pi] = dd / (nrm[i] * nrm[j]);
                ++pi;
            }
    }
}

// ---- C: zraw quarter-slices; 4-way p-interleaved loads for MLP ----
__global__ __launch_bounds__(256) void kC(const float* __restrict__ x,
                                          float* __restrict__ ws) {
    const int bt = blockIdx.x;
    const int qq = blockIdx.y;             // p-quarter
    const int t = threadIdx.x;             // dim group d0 = t*4
    __shared__ __attribute__((aligned(16))) float w_s[64 * 16];
    for (int idx = t; idx < 1024; idx += 256) {
        int p = idx >> 4, nh = idx & 15;
        w_s[idx] = ws[OFF_W + (size_t)(bt * NH16 + nh) * NPATCH + qq * 64 + p];
    }
    float4 acc[16];
    #pragma unroll
    for (int i = 0; i < 16; ++i) { acc[i].x = 0.f; acc[i].y = 0.f; acc[i].z = 0.f; acc[i].w = 0.f; }
    __syncthreads();
    const float* xp = x + (size_t)(bt * NPATCH + qq * 64) * DV + t * 4;
    #define FMA4(k, wgt, xv) acc[k].x += (wgt) * xv.x; acc[k].y += (wgt) * xv.y; \
                             acc[k].z += (wgt) * xv.z; acc[k].w += (wgt) * xv.w;
    #define PBLOCK(p, xv) { \
        float4 a0 = *(const float4*)&w_s[(p) * 16 + 0]; \
        float4 a1 = *(const float4*)&w_s[(p) * 16 + 4]; \
        float4 a2 = *(const float4*)&w_s[(p) * 16 + 8]; \
        float4 a3 = *(const float4*)&w_s[(p) * 16 + 12]; \
        FMA4(0, a0.x, xv)  FMA4(1, a0.y, xv)  FMA4(2, a0.z, xv)  FMA4(3, a0.w, xv) \
        FMA4(4, a1.x, xv)  FMA4(5, a1.y, xv)  FMA4(6, a1.z, xv)  FMA4(7, a1.w, xv) \
        FMA4(8, a2.x, xv)  FMA4(9, a2.y, xv)  FMA4(10, a2.z, xv) FMA4(11, a2.w, xv) \
        FMA4(12, a3.x, xv) FMA4(13, a3.y, xv) FMA4(14, a3.z, xv) FMA4(15, a3.w, xv) }
    for (int p = 0; p < 16; ++p) {
        float4 xv0 = *(const float4*)(xp + (size_t)(p +  0) * DV);
        float4 xv1 = *(const float4*)(xp + (size_t)(p + 16) * DV);
        float4 xv2 = *(const float4*)(xp + (size_t)(p + 32) * DV);
        float4 xv3 = *(const float4*)(xp + (size_t)(p + 48) * DV);
        PBLOCK(p, xv0)
        PBLOCK(p + 16, xv1)
        PBLOCK(p + 32, xv2)
        PBLOCK(p + 48, xv3)
    }
    #undef PBLOCK
    #undef FMA4
    #pragma unroll
    for (int nh = 0; nh < 16; ++nh)
        *(float4*)(ws + OFF_XBAR + (size_t)qq * XSLICE
                   + ((size_t)bt * NH16 + nh) * DV + t * 4) = acc[nh];
}

// ---- D1: pooled = (zraw - CV)*g@Wv folded; grid 256 = 16 nh x 16 btg ----
__global__ __launch_bounds__(256) void kD1(const float* __restrict__ Wv,
                                           const float* __restrict__ g,
                                           const float* __restrict__ b,
                                           const float* __restrict__ bv,
                                           float* __restrict__ ws) {
    const int nh = blockIdx.x & 15, btg = blockIdx.x >> 4;
    const int n = nh >> 2, h = nh & 3;
    const int bt0 = btg * 8, cb = h * 64;
    __shared__ __attribute__((aligned(16))) float xs[8][1024];
    __shared__ __attribute__((aligned(16))) float gs[1024], bs[1024];
    __shared__ float red[4][64][10];
    const int t = threadIdx.x;
    for (int e = t; e < 2048; e += 256) {
        const int bt = e >> 8, i4 = e & 255;
        const size_t b0 = OFF_XBAR + ((size_t)(bt0 + bt) * NH16 + nh) * DV + i4 * 4;
        float4 s = {0.f, 0.f, 0.f, 0.f};
        #pragma unroll
        for (int qq = 0; qq < 4; ++qq) {
            float4 v = *(const float4*)(ws + b0 + (size_t)qq * XSLICE);
            s.x += v.x; s.y += v.y; s.z += v.z; s.w += v.w;
        }
        *(float4*)&xs[bt][i4 * 4] = s;
    }
    for (int e = t; e < 1024; e += 256) { gs[e] = g[e]; bs[e] = b[e]; }
    __syncthreads();
    const int c = t & 63, sub = t >> 6;
    float acc[8];
    #pragma unroll
    for (int l = 0; l < 8; ++l) acc[l] = 0.f;
    float gv = 0.f, bvv = 0.f;
    const float* wvp = Wv + ((size_t)n * DV + sub * 256) * DB + cb + c;
    const int ib0 = sub * 256;
    #pragma unroll 2
    for (int gidx = 0; gidx < 64; ++gidx) {
        const int ib = ib0 + gidx * 4;
        float w0 = wvp[(size_t)(gidx * 4 + 0) * DB];
        float w1 = wvp[(size_t)(gidx * 4 + 1) * DB];
        float w2 = wvp[(size_t)(gidx * 4 + 2) * DB];
        float w3 = wvp[(size_t)(gidx * 4 + 3) * DB];
        float4 g4 = *(const float4*)&gs[ib];
        float4 b4 = *(const float4*)&bs[ib];
        float q0 = g4.x * w0, q1 = g4.y * w1, q2 = g4.z * w2, q3 = g4.w * w3;
        gv  += q0 + q1 + q2 + q3;
        bvv += b4.x * w0 + b4.y * w1 + b4.z * w2 + b4.w * w3;
        #pragma unroll
        for (int l = 0; l < 8; ++l) {
            float4 xr = *(const float4*)&xs[l][ib];
            acc[l] += xr.x * q0 + xr.y * q1 + xr.z * q2 + xr.w * q3;
        }
    }
    #pragma unroll
    for (int l = 0; l < 8; ++l) red[sub][c][l] = acc[l];
    red[sub][c][8] = gv; red[sub][c][9] = bvv;
    __syncthreads();
    const int c2 = t & 63, l0 = t >> 6;
    float gvS = red[0][c2][8] + red[1][c2][8] + red[2][c2][8] + red[3][c2][8];
    float bvS = red[0][c2][9] + red[1][c2][9] + red[2][c2][9] + red[3][c2][9];
    float base = bv[n * DB + cb + c2] + bvS;
    #pragma unroll
    for (int li = 0; li < 2; ++li) {
        const int l = l0 + li * 4;
        float p = red[0][c2][l] + red[1][c2][l] + red[2][c2][l] + red[3][c2][l];
        float C = ws[OFF_CV + (bt0 + l) * NH16 + nh];
        ws[OFF_POOL + ((size_t)n * BT + bt0 + l) * DB + cb + c2] = p - C * gvS + base;
    }
}

// ---- D2: out = pooled @ Wo + bo ; block 0 also finalizes diversity loss ----
__global__ __launch_bounds__(256) void kD2(const float* __restrict__ Wo,
                                           const float* __restrict__ bo,
                                           const float* __restrict__ ws,
                                           float* __restrict__ out) {
    const int btg = blockIdx.x & 15, jq = (blockIdx.x >> 4) & 3, n = blockIdx.x >> 6;
    const int bt0 = btg * 8, j0 = jq * 64;
    __shared__ __attribute__((aligned(16))) float ps[8][256];
    __shared__ float red[4][64][8];
    __shared__ float dred[4];
    const int t = threadIdx.x;
    for (int e = t; e < 512; e += 256) {
        const int bt = e >> 6, c4 = e & 63;
        *(float4*)&ps[bt][c4 * 4] =
            *(const float4*)(ws + OFF_POOL + ((size_t)n * BT + bt0 + bt) * DB + c4 * 4);
    }
    float dacc = 0.f;
    if (blockIdx.x == 0)
        for (int idx = t; idx < 768; idx += 256) dacc += ws[OFF_DIV + idx];
    for (int d = 1; d < 64; d <<= 1) dacc += __shfl_xor(dacc, d);
    if ((t & 63) == 0) dred[t >> 6] = dacc;
    __syncthreads();
    if (blockIdx.x == 0 && t == 0)
        out[131072] = 0.1f * (dred[0] + dred[1] + dred[2] + dred[3]) / 768.f;
    const int j = t & 63, sub = t >> 6;
    float acc[8];
    #pragma unroll
    for (int l = 0; l < 8; ++l) acc[l] = 0.f;
    const float* wop = Wo + ((size_t)n * DB + sub * 64) * DB + j0 + j;
    const int cb0 = sub * 64;
    #pragma unroll 2
    for (int gidx = 0; gidx < 16; ++gidx) {
        const int cb = cb0 + gidx * 4;
        float w0 = wop[(size_t)(gidx * 4 + 0) * DB];
        float w1 = wop[(size_t)(gidx * 4 + 1) * DB];
        float w2 = wop[(size_t)(gidx * 4 + 2) * DB];
        float w3 = wop[(size_t)(gidx * 4 + 3) * DB];
        #pragma unroll
        for (int l = 0; l < 8; ++l) {
            float4 pr = *(const float4*)&ps[l][cb];
            acc[l] += pr.x * w0 + pr.y * w1 + pr.z * w2 + pr.w * w3;
        }
    }
    #pragma unroll
    for (int l = 0; l < 8; ++l) red[sub][j][l] = acc[l];
    __syncthreads();
    const int j2 = t & 63, l0 = t >> 6;
    float bov = bo[n * DB + j0 + j2];
    #pragma unroll
    for (int li = 0; li < 2; ++li) {
        const int l = l0 + li * 4;
        float o = red[0][j2][l] + red[1][j2][l] + red[2][j2][l] + red[3][j2][l] + bov;
        out[((size_t)(bt0 + l) * NB + n) * DB + j0 + j2] = o;
    }
}

extern "C" void kernel_launch(void* const* d_in, const int* in_sizes, int n_in,
                              void* d_out, int out_size, void* d_ws, size_t ws_size,
                              hipStream_t stream) {
    const float* x  = (const float*)d_in[0];
    const float* g  = (const float*)d_in[1];
    const float* b  = (const float*)d_in[2];
    const float* q  = (const float*)d_in[3];
    const float* Wk = (const float*)d_in[4];
    const float* bk = (const float*)d_in[5];
    const float* Wv = (const float*)d_in[6];
    const float* bv = (const float*)d_in[7];
    const float* Wo = (const float*)d_in[8];
    const float* bo = (const float*)d_in[9];
    float* out = (float*)d_out;
    float* ws  = (float*)d_ws;

    hipLaunchKernelGGL(kP,  dim3(256),    dim3(256), 0, stream, Wk, q, g, b, ws);
    hipLaunchKernelGGL(kA,  dim3(512),    dim3(256), 0, stream, x, ws);
    hipLaunchKernelGGL(kB,  dim3(128),    dim3(256), 0, stream, q, bk, ws);
    hipLaunchKernelGGL(kC,  dim3(128, 4), dim3(256), 0, stream, x, ws);
    hipLaunchKernelGGL(kD1, dim3(256),    dim3(256), 0, stream, Wv, g, b, bv, ws);
    hipLaunchKernelGGL(kD2, dim3(256),    dim3(256), 0, stream, Wo, bo, ws, out);
}